// Round 2
// baseline (592.984 us; speedup 1.0000x reference)
//
#include <hip/hip_runtime.h>
#include <stdint.h>

// Ising PT sampler, bit-exact replay of the JAX threefry2x32 reference
// under the MODERN default jax_threefry_partitionable=True:
//   random_bits flat idx i -> block counter (0, i), bits = o0 ^ o1
//   split(key) -> k1 = tf(key,(0,0)), k2 = tf(key,(0,1))   [foldlike]
//   fold_in(key, d) -> tf(key,(0,d))                        [flag-independent]
// B=16 chains x C=16 replicas x 128x128 lattice, 20 sweeps total,
// PT exchange after sweeps 0,5,10,15; samples captured after sweeps 14,19.

#define LSZ   128
#define NB    16
#define NC    16
#define NSITES (NB*NC*LSZ*LSZ)     // 4194304

// ---------------- threefry2x32 (JAX/Random123, 20 rounds) ----------------
__host__ __device__ __forceinline__ void tf2x32(uint32_t k0, uint32_t k1,
                                                uint32_t x0, uint32_t x1,
                                                uint32_t& o0, uint32_t& o1) {
  uint32_t k2 = k0 ^ k1 ^ 0x1BD11BDAu;
  x0 += k0; x1 += k1;
#define TFR(r) { x0 += x1; x1 = (x1 << (r)) | (x1 >> (32 - (r))); x1 ^= x0; }
  TFR(13) TFR(15) TFR(26) TFR(6)
  x0 += k1; x1 += k2 + 1u;
  TFR(17) TFR(29) TFR(16) TFR(24)
  x0 += k2; x1 += k0 + 2u;
  TFR(13) TFR(15) TFR(26) TFR(6)
  x0 += k0; x1 += k1 + 3u;
  TFR(17) TFR(29) TFR(16) TFR(24)
  x0 += k1; x1 += k2 + 4u;
  TFR(13) TFR(15) TFR(26) TFR(6)
  x0 += k2; x1 += k0 + 5u;
#undef TFR
  o0 = x0; o1 = x1;
}

// jax.random.uniform bit->float: bitcast((bits>>9)|0x3f800000) - 1.0f
__device__ __forceinline__ float tf_uniform(uint32_t w) {
  union { uint32_t u; float f; } cvt;
  cvt.u = (w >> 9) | 0x3f800000u;
  return cvt.f - 1.0f;
}

// ---------------- kernels ----------------

// float32 (+-1) -> int8 lattice
__global__ __launch_bounds__(256) void k_init(const float4* __restrict__ in,
                                              char4* __restrict__ s4) {
  int t = blockIdx.x * 256 + threadIdx.x;     // < NSITES/4
  float4 v = in[t];
  char4 o;
  o.x = v.x >= 0.0f ? 1 : -1;
  o.y = v.y >= 0.0f ? 1 : -1;
  o.z = v.z >= 0.0f ? 1 : -1;
  o.w = v.w >= 0.0f ? 1 : -1;
  s4[t] = o;
}

// One checkerboard half-update. parity=0: black ((i+j)%2==0), parity=1: white.
// One thread per masked site; one threefry block per site, counter (0, idx),
// bits = o0 ^ o1 (partitionable scheme).
__global__ __launch_bounds__(256) void k_half(int8_t* __restrict__ s,
                                              const float* __restrict__ T,
                                              uint32_t kk0, uint32_t kk1,
                                              int parity) {
  __shared__ float P[NB][2];   // P[b][0]=exp(-4/T[b]), P[b][1]=exp(-8/T[b])
  int t = threadIdx.x;
  if (t < 2 * NB) {
    int b = t >> 1, e = t & 1;
    float x = (e ? -8.0f : -4.0f) / T[b];     // float32 IEEE divide, as ref
    P[b][e] = (float)exp((double)x);          // correctly-rounded f32 exp
  }
  __syncthreads();

  int tid = blockIdx.x * 256 + t;             // < 2097152
  int jj  = tid & 63;
  int ri  = (tid >> 6) & 127;
  int bc  = tid >> 13;                        // b*16+c, < 256
  int b   = bc >> 4;
  int j   = (jj << 1) | ((ri + parity) & 1);

  int base = bc << 14;
  int idx  = base + (ri << 7) + j;
  int up   = base + (((ri - 1) & 127) << 7) + j;
  int dn   = base + (((ri + 1) & 127) << 7) + j;
  int lf   = base + (ri << 7) + ((j - 1) & 127);
  int rt   = base + (ri << 7) + ((j + 1) & 127);

  int s0 = s[idx];
  int n0 = (int)s[up] + s[dn] + s[lf] + s[rt];

  uint32_t o0, o1;
  tf2x32(kk0, kk1, 0u, (uint32_t)idx, o0, o1);
  float u = tf_uniform(o0 ^ o1);

  int dE0 = 2 * s0 * n0;                      // in {-8,-4,0,4,8}
  bool a0 = (dE0 <= 0) || (u < P[b][dE0 == 8 ? 1 : 0]);
  if (a0) s[idx] = (int8_t)(-s0);
}

// Per-(b,c) energy: E = -sum s*(down+right). Exact integer in f32.
__global__ __launch_bounds__(256) void k_energy(const int8_t* __restrict__ s,
                                                float* __restrict__ E) {
  __shared__ int red[256];
  int bc = blockIdx.x;                         // < 256
  const int8_t* p = s + (bc << 14);
  int t = threadIdx.x;
  int acc = 0;
  for (int m = t; m < LSZ * LSZ; m += 256) {
    int ri = m >> 7, j = m & 127;
    int sv = p[m];
    int dnv = p[(((ri + 1) & 127) << 7) | j];
    int rtv = p[(ri << 7) | ((j + 1) & 127)];
    acc += sv * (dnv + rtv);
  }
  red[t] = acc;
  __syncthreads();
  for (int o = 128; o > 0; o >>= 1) {
    if (t < o) red[t] += red[t + o];
    __syncthreads();
  }
  if (t == 0) E[bc] = -(float)red[0];
}

// PT accept decisions: 128 threads, t = p*16+c for pair p (chains 2p,2p+1).
__global__ __launch_bounds__(128) void k_decide(const float* __restrict__ E,
                                                const float* __restrict__ T,
                                                uint32_t pk0, uint32_t pk1,
                                                int* __restrict__ acc) {
  int t = threadIdx.x;                         // < 128
  int p = t >> 4, c = t & 15;
  float E0 = E[(2 * p) * NC + c];
  float E1 = E[(2 * p + 1) * NC + c];
  float b0 = 1.0f / T[2 * p];
  float b1 = 1.0f / T[2 * p + 1];
  float d = (b0 - b1) * (E0 - E1);
  // partitionable bits: elem t -> block (0, t), xor words
  uint32_t w0, w1;
  tf2x32(pk0, pk1, 0u, (uint32_t)t, w0, w1);
  float u = tf_uniform(w0 ^ w1);
  float pa = 1.0f;
  if (d < 0.0f) pa = (float)exp((double)d);
  acc[t] = (u < pa) ? 1 : 0;
}

// Swap accepted pairs (whole lattice), 4 bytes per thread.
__global__ __launch_bounds__(256) void k_swap(uint32_t* __restrict__ s32,
                                              const int* __restrict__ acc) {
  int t = blockIdx.x * 256 + threadIdx.x;      // < 524288
  int m = t & 4095;
  int pc = t >> 12;                            // p*16+c, < 128
  if (!acc[pc]) return;
  int p = pc >> 4, c = pc & 15;
  int i0 = (((2 * p) * NC + c) << 12) + m;
  int i1 = (((2 * p + 1) * NC + c) << 12) + m;
  uint32_t v0 = s32[i0], v1 = s32[i1];
  s32[i0] = v1;
  s32[i1] = v0;
}

// Write sample sidx: out[b][sidx*16+c][i][j] = spins, int8 -> float
__global__ __launch_bounds__(256) void k_sample(const uint32_t* __restrict__ s32,
                                                float4* __restrict__ out4,
                                                int sidx) {
  int w = blockIdx.x * 256 + threadIdx.x;      // < 1048576
  int m = w & 4095;
  int pc = w >> 12;                            // b*16+c, b<16
  int c = pc & 15, b = pc >> 4;
  uint32_t v = s32[w];
  float4 o;
  o.x = (float)(int)(int8_t)(v & 0xFF);
  o.y = (float)(int)(int8_t)((v >> 8) & 0xFF);
  o.z = (float)(int)(int8_t)((v >> 16) & 0xFF);
  o.w = (float)(int)(int8_t)((v >> 24) & 0xFF);
  out4[((b * 32 + sidx * NC + c) << 12) + m] = o;
}

// ---------------- host ----------------
extern "C" void kernel_launch(void* const* d_in, const int* in_sizes, int n_in,
                              void* d_out, int out_size, void* d_ws, size_t ws_size,
                              hipStream_t stream) {
  const float* spins_in = (const float*)d_in[0];
  const float* T        = (const float*)d_in[1];
  // schedule constants per setup_inputs: n_sweeps=10, n_therm=10,
  // decorrelate=5, pt_interval=5  -> 20 sweeps, PT at 0,5,10,15,
  // samples after sweeps 14 and 19.
  int8_t* s   = (int8_t*)d_ws;                            // 4 MB lattice
  float*  E   = (float*)((char*)d_ws + (4u << 20));       // 256 floats
  int*    acc = (int*)((char*)d_ws + (4u << 20) + 4096);  // 128 ints
  float*  out = (float*)d_out;

  k_init<<<NSITES / 4 / 256, 256, 0, stream>>>((const float4*)spins_in, (char4*)s);

  const uint32_t bk0 = 0u, bk1 = 42u;   // jax.random.key(42)
  for (int i = 0; i < 20; ++i) {
    uint32_t kk0, kk1;
    tf2x32(bk0, bk1, 0u, (uint32_t)i, kk0, kk1);          // fold_in(base, i)
    // foldlike split: k1 = tf(k,(0,0)), k2 = tf(k,(0,1))
    uint32_t k1a, k1b, k2a, k2b;
    tf2x32(kk0, kk1, 0u, 0u, k1a, k1b);
    tf2x32(kk0, kk1, 0u, 1u, k2a, k2b);

    k_half<<<2097152 / 256, 256, 0, stream>>>(s, T, k1a, k1b, 0);  // black
    k_half<<<2097152 / 256, 256, 0, stream>>>(s, T, k2a, k2b, 1);  // white

    if (i % 5 == 0) {
      uint32_t p0, p1;
      tf2x32(kk0, kk1, 0u, 123u, p0, p1);                 // fold_in(k, 123)
      k_energy<<<256, 256, 0, stream>>>(s, E);
      k_decide<<<1, 128, 0, stream>>>(E, T, p0, p1, acc);
      k_swap<<<524288 / 256, 256, 0, stream>>>((uint32_t*)s, acc);
    }
    if (i == 14) k_sample<<<1048576 / 256, 256, 0, stream>>>((const uint32_t*)s, (float4*)out, 0);
    if (i == 19) k_sample<<<1048576 / 256, 256, 0, stream>>>((const uint32_t*)s, (float4*)out, 1);
  }
}

// Round 5
// 419.065 us; speedup vs baseline: 1.4150x; 1.4150x over previous
//
#include <hip/hip_runtime.h>
#include <stdint.h>

// Ising PT sampler, bit-exact replay of JAX threefry2x32 (partitionable).
// R5: R2's proven launch skeleton (separate half-sweep dispatches, physical
// swap, no LDS residency) + vectorized segment math in k_half only:
// one thread per (lattice, row, 16-col segment), uint4 loads, 8 sites/thread.

#define LSZ   128
#define NB    16
#define NC    16
#define NSITES (NB*NC*LSZ*LSZ)     // 4194304

// ---------------- threefry2x32 (JAX/Random123, 20 rounds) ----------------
__host__ __device__ __forceinline__ void tf2x32(uint32_t k0, uint32_t k1,
                                                uint32_t x0, uint32_t x1,
                                                uint32_t& o0, uint32_t& o1) {
  uint32_t k2 = k0 ^ k1 ^ 0x1BD11BDAu;
  x0 += k0; x1 += k1;
#define TFR(r) { x0 += x1; x1 = (x1 << (r)) | (x1 >> (32 - (r))); x1 ^= x0; }
  TFR(13) TFR(15) TFR(26) TFR(6)
  x0 += k1; x1 += k2 + 1u;
  TFR(17) TFR(29) TFR(16) TFR(24)
  x0 += k2; x1 += k0 + 2u;
  TFR(13) TFR(15) TFR(26) TFR(6)
  x0 += k0; x1 += k1 + 3u;
  TFR(17) TFR(29) TFR(16) TFR(24)
  x0 += k1; x1 += k2 + 4u;
  TFR(13) TFR(15) TFR(26) TFR(6)
  x0 += k2; x1 += k0 + 5u;
#undef TFR
  o0 = x0; o1 = x1;
}

__device__ __forceinline__ float tf_uniform(uint32_t w) {
  union { uint32_t u; float f; } cvt;
  cvt.u = (w >> 9) | 0x3f800000u;
  return cvt.f - 1.0f;
}

// signed byte b (compile-time 0..3) of word w
__device__ __forceinline__ int sb(uint32_t w, int b) {
  return (int)((int32_t)(w << ((3 - b) * 8)) >> 24);
}

// ---------------- kernels ----------------

// float32 (+-1) -> packed int8 lattice (same as proven R2 k_init)
__global__ __launch_bounds__(256) void k_init(const float4* __restrict__ in,
                                              uint32_t* __restrict__ s4) {
  int t = blockIdx.x * 256 + threadIdx.x;     // < NSITES/4
  float4 v = in[t];
  uint32_t o = (v.x >= 0.0f ? 0x01u : 0xFFu)
             | ((v.y >= 0.0f ? 0x01u : 0xFFu) << 8)
             | ((v.z >= 0.0f ? 0x01u : 0xFFu) << 16)
             | ((v.w >= 0.0f ? 0x01u : 0xFFu) << 24);
  s4[t] = o;
}

// One checkerboard half-update, vectorized: thread = (bc, row, 16-col seg).
// 262144 threads, 8 masked sites each.
__global__ __launch_bounds__(256) void k_half(uint32_t* __restrict__ s,
                                              const float* __restrict__ T,
                                              uint32_t kk0, uint32_t kk1,
                                              int parity) {
  __shared__ float P[NB][2];   // P[b][0]=exp(-4/T[b]), P[b][1]=exp(-8/T[b])
  int t = threadIdx.x;
  if (t < 2 * NB) {
    int b = t >> 1, e = t & 1;
    float x = (e ? -8.0f : -4.0f) / T[b];     // ref: f32 div, f32 exp
    P[b][e] = (float)exp((double)x);
  }
  __syncthreads();

  int tid = blockIdx.x * 256 + t;             // < 262144
  int seg  = tid & 7;                         // 16-col segment
  int r    = (tid >> 3) & 127;                // row
  int bc   = tid >> 10;                       // b*16+c, < 256
  int b    = bc >> 4;
  int col0 = seg << 4;
  int j0   = (r + parity) & 1;                // parity offset of masked cols

  const uint4* s4 = (const uint4*)s;
  const int8_t* s8 = (const int8_t*)s;
  int base4 = bc << 10;                       // uint4 index of lattice start
  int baseB = bc << 14;                       // byte index

  uint4 cv = s4[base4 + (r << 3) + seg];
  uint4 uv = s4[base4 + (((r - 1) & 127) << 3) + seg];
  uint4 dv = s4[base4 + (((r + 1) & 127) << 3) + seg];
  int lfb = s8[baseB + (r << 7) + ((col0 - 1) & 127)];
  int rtb = s8[baseB + (r << 7) + ((col0 + 16) & 127)];

  uint32_t cw[4] = {cv.x, cv.y, cv.z, cv.w};
  uint32_t uw[4] = {uv.x, uv.y, uv.z, uv.w};
  uint32_t dw[4] = {dv.x, dv.y, dv.z, dv.w};

  // extended window X[0..17] = {lfb, cur[0..15], rtb}; Y byte k = X[k+j0]
  uint32_t ext[5];
  ext[0] = (cw[0] << 8) | (uint32_t)(uint8_t)lfb;
  ext[1] = (cw[0] >> 24) | (cw[1] << 8);
  ext[2] = (cw[1] >> 24) | (cw[2] << 8);
  ext[3] = (cw[2] >> 24) | (cw[3] << 8);
  ext[4] = (cw[3] >> 24) | ((uint32_t)(uint8_t)rtb << 8);
  uint32_t Y[5], U[4], D[4];
#pragma unroll
  for (int i = 0; i < 4; ++i) {
    uint32_t sh = (ext[i] >> 8) | (ext[i + 1] << 24);
    Y[i] = j0 ? sh : ext[i];
    uint32_t su = (uw[i] >> 8) | ((i < 3 ? uw[i + 1] : 0u) << 24);
    U[i] = j0 ? su : uw[i];
    uint32_t sd = (dw[i] >> 8) | ((i < 3 ? dw[i + 1] : 0u) << 24);
    D[i] = j0 ? sd : dw[i];
  }
  Y[4] = j0 ? (ext[4] >> 8) : ext[4];

  const float p4 = P[b][0], p8 = P[b][1];
  const uint32_t mbase = 0xFEu << (8 * j0);   // XOR flips 0x01<->0xFF
  uint32_t xm[4] = {0u, 0u, 0u, 0u};
  const uint32_t cnt0 = (uint32_t)(baseB + (r << 7) + col0 + j0);
#pragma unroll
  for (int m = 0; m < 8; ++m) {
    int lf = sb(Y[(2 * m) >> 2], (2 * m) & 3);
    int s0 = sb(Y[(2 * m + 1) >> 2], (2 * m + 1) & 3);
    int rt = sb(Y[(2 * m + 2) >> 2], (2 * m + 2) & 3);
    int up = sb(U[(2 * m) >> 2], (2 * m) & 3);
    int dn = sb(D[(2 * m) >> 2], (2 * m) & 3);
    int q = s0 * (lf + rt + up + dn);         // dE = 2*q
    uint32_t o0, o1;
    tf2x32(kk0, kk1, 0u, cnt0 + 2u * (uint32_t)m, o0, o1);
    float u = tf_uniform(o0 ^ o1);
    bool a = (q <= 0) || (u < (q == 4 ? p8 : p4));
    if (a) xm[m >> 1] |= (m & 1) ? (mbase << 16) : mbase;
  }
  uint4 nv;
  nv.x = cw[0] ^ xm[0]; nv.y = cw[1] ^ xm[1];
  nv.z = cw[2] ^ xm[2]; nv.w = cw[3] ^ xm[3];
  ((uint4*)s)[base4 + (r << 3) + seg] = nv;
}

// Per-(b,c) energy: E = -sum s*(down+right). Exact integer in f32. (R2 proven)
__global__ __launch_bounds__(256) void k_energy(const int8_t* __restrict__ s,
                                                float* __restrict__ E) {
  __shared__ int red[256];
  int bc = blockIdx.x;                         // < 256
  const int8_t* p = s + (bc << 14);
  int t = threadIdx.x;
  int acc = 0;
  for (int m = t; m < LSZ * LSZ; m += 256) {
    int ri = m >> 7, j = m & 127;
    int sv = p[m];
    int dnv = p[(((ri + 1) & 127) << 7) | j];
    int rtv = p[(ri << 7) | ((j + 1) & 127)];
    acc += sv * (dnv + rtv);
  }
  red[t] = acc;
  __syncthreads();
  for (int o = 128; o > 0; o >>= 1) {
    if (t < o) red[t] += red[t + o];
    __syncthreads();
  }
  if (t == 0) E[bc] = -(float)red[0];
}

// PT accept decisions: 128 threads, t = p*16+c for pair p. (R2 proven)
__global__ __launch_bounds__(128) void k_decide(const float* __restrict__ E,
                                                const float* __restrict__ T,
                                                uint32_t pk0, uint32_t pk1,
                                                int* __restrict__ acc) {
  int t = threadIdx.x;                         // < 128
  int p = t >> 4, c = t & 15;
  float E0 = E[(2 * p) * NC + c];
  float E1 = E[(2 * p + 1) * NC + c];
  float b0 = 1.0f / T[2 * p];
  float b1 = 1.0f / T[2 * p + 1];
  float d = (b0 - b1) * (E0 - E1);
  uint32_t w0, w1;
  tf2x32(pk0, pk1, 0u, (uint32_t)t, w0, w1);
  float u = tf_uniform(w0 ^ w1);
  float pa = (d < 0.0f) ? (float)exp((double)d) : 1.0f;
  acc[t] = (u < pa) ? 1 : 0;
}

// Swap accepted pairs (whole lattice), 4 bytes per thread. (R2 proven)
__global__ __launch_bounds__(256) void k_swap(uint32_t* __restrict__ s32,
                                              const int* __restrict__ acc) {
  int t = blockIdx.x * 256 + threadIdx.x;      // < 524288
  int m = t & 4095;
  int pc = t >> 12;                            // p*16+c, < 128
  if (!acc[pc]) return;
  int p = pc >> 4, c = pc & 15;
  int i0 = (((2 * p) * NC + c) << 12) + m;
  int i1 = (((2 * p + 1) * NC + c) << 12) + m;
  uint32_t v0 = s32[i0], v1 = s32[i1];
  s32[i0] = v1;
  s32[i1] = v0;
}

// Write sample sidx: out[b][sidx*16+c][i][j] = spins, int8 -> float (R2 proven)
__global__ __launch_bounds__(256) void k_sample(const uint32_t* __restrict__ s32,
                                                float4* __restrict__ out4,
                                                int sidx) {
  int w = blockIdx.x * 256 + threadIdx.x;      // < 1048576
  int m = w & 4095;
  int pc = w >> 12;                            // b*16+c, b<16
  int c = pc & 15, b = pc >> 4;
  uint32_t v = s32[w];
  float4 o;
  o.x = (float)(int)(int8_t)(v & 0xFF);
  o.y = (float)(int)(int8_t)((v >> 8) & 0xFF);
  o.z = (float)(int)(int8_t)((v >> 16) & 0xFF);
  o.w = (float)(int)(int8_t)((v >> 24) & 0xFF);
  out4[((b * 32 + sidx * NC + c) << 12) + m] = o;
}

// ---------------- host ----------------
extern "C" void kernel_launch(void* const* d_in, const int* in_sizes, int n_in,
                              void* d_out, int out_size, void* d_ws, size_t ws_size,
                              hipStream_t stream) {
  const float* spins_in = (const float*)d_in[0];
  const float* T        = (const float*)d_in[1];
  uint32_t* s = (uint32_t*)d_ws;                          // 4 MB lattice
  float*  E   = (float*)((char*)d_ws + (4u << 20));       // 256 floats
  int*    acc = (int*)((char*)d_ws + (4u << 20) + 4096);  // 128 ints
  float*  out = (float*)d_out;

  k_init<<<NSITES / 4 / 256, 256, 0, stream>>>((const float4*)spins_in, s);

  const uint32_t bk0 = 0u, bk1 = 42u;   // jax.random.key(42)
  for (int i = 0; i < 20; ++i) {
    uint32_t kk0, kk1;
    tf2x32(bk0, bk1, 0u, (uint32_t)i, kk0, kk1);          // fold_in(base, i)
    uint32_t k1a, k1b, k2a, k2b;
    tf2x32(kk0, kk1, 0u, 0u, k1a, k1b);                   // split -> k1 (black)
    tf2x32(kk0, kk1, 0u, 1u, k2a, k2b);                   // split -> k2 (white)

    k_half<<<262144 / 256, 256, 0, stream>>>(s, T, k1a, k1b, 0);  // black
    k_half<<<262144 / 256, 256, 0, stream>>>(s, T, k2a, k2b, 1);  // white

    if (i % 5 == 0) {
      uint32_t p0, p1;
      tf2x32(kk0, kk1, 0u, 123u, p0, p1);                 // fold_in(k, 123)
      k_energy<<<256, 256, 0, stream>>>((const int8_t*)s, E);
      k_decide<<<1, 128, 0, stream>>>(E, T, p0, p1, acc);
      k_swap<<<524288 / 256, 256, 0, stream>>>(s, acc);
    }
    if (i == 14) k_sample<<<1048576 / 256, 256, 0, stream>>>(s, (float4*)out, 0);
    if (i == 19) k_sample<<<1048576 / 256, 256, 0, stream>>>(s, (float4*)out, 1);
  }
}

// Round 6
// 292.029 us; speedup vs baseline: 2.0306x; 1.4350x over previous
//
#include <hip/hip_runtime.h>
#include <stdint.h>

// Ising PT sampler, bit-exact replay of JAX threefry2x32 (partitionable).
// R6: fused chunk kernels (lattice LDS-resident across sweeps between PT
// events; PT = slot relabel; energy+sample fused into chunk epilogue).
// R3/R4 crash root-caused: slotmap was initialized with lattice ids (0..255)
// but consumed as chain rows (0..15) -> OOB sample write. Fixed here:
// slotmap[w] = w >> 4.

#define LSZ   128
#define NB    16
#define NC    16
#define NSITES (NB*NC*LSZ*LSZ)     // 4194304

// ---------------- threefry2x32 (JAX/Random123, 20 rounds) ----------------
__host__ __device__ __forceinline__ void tf2x32(uint32_t k0, uint32_t k1,
                                                uint32_t x0, uint32_t x1,
                                                uint32_t& o0, uint32_t& o1) {
  uint32_t k2 = k0 ^ k1 ^ 0x1BD11BDAu;
  x0 += k0; x1 += k1;
#define TFR(r) { x0 += x1; x1 = (x1 << (r)) | (x1 >> (32 - (r))); x1 ^= x0; }
  TFR(13) TFR(15) TFR(26) TFR(6)
  x0 += k1; x1 += k2 + 1u;
  TFR(17) TFR(29) TFR(16) TFR(24)
  x0 += k2; x1 += k0 + 2u;
  TFR(13) TFR(15) TFR(26) TFR(6)
  x0 += k0; x1 += k1 + 3u;
  TFR(17) TFR(29) TFR(16) TFR(24)
  x0 += k1; x1 += k2 + 4u;
  TFR(13) TFR(15) TFR(26) TFR(6)
  x0 += k2; x1 += k0 + 5u;
#undef TFR
  o0 = x0; o1 = x1;
}

__device__ __forceinline__ float tf_uniform(uint32_t w) {
  union { uint32_t u; float f; } cvt;
  cvt.u = (w >> 9) | 0x3f800000u;
  return cvt.f - 1.0f;
}

// signed byte b (compile-time 0..3) of word w
__device__ __forceinline__ int sb(uint32_t w, int b) {
  return (int)((int32_t)(w << ((3 - b) * 8)) >> 24);
}

// ---------------- kernels ----------------

// float32 (+-1) -> packed int8 lattice; slotmap[w] = chain ROW (w>>4);
// occ[row*16+c] = lattice id at that (row, c).
__global__ __launch_bounds__(256) void k_init(const float4* __restrict__ in,
                                              uint32_t* __restrict__ s4,
                                              int* __restrict__ slotmap,
                                              int* __restrict__ occ) {
  int t = blockIdx.x * 256 + threadIdx.x;     // < NSITES/4
  float4 v = in[t];
  uint32_t o = (v.x >= 0.0f ? 0x01u : 0xFFu)
             | ((v.y >= 0.0f ? 0x01u : 0xFFu) << 8)
             | ((v.z >= 0.0f ? 0x01u : 0xFFu) << 16)
             | ((v.w >= 0.0f ? 0x01u : 0xFFu) << 24);
  s4[t] = o;
  if (t < 256) { slotmap[t] = t >> 4; occ[t] = t; }
}

// One chunk of sweeps, lattice resident in LDS.
// blockIdx = lattice id w (fixed storage slot); chain row = slotmap[w] (0..15).
__global__ __launch_bounds__(1024) void k_chunk(uint32_t* __restrict__ sg,
                                                const float* __restrict__ T,
                                                const int* __restrict__ slotmap,
                                                float* __restrict__ E,
                                                float* __restrict__ out,
                                                uint4 K0, uint4 K1, uint4 K2,
                                                uint4 K3, uint4 K4,
                                                int nsw, int sample_local,
                                                int sidx, int write_E) {
  __shared__ __align__(16) uint32_t lat32[LSZ * LSZ / 4];   // 16 KB
  __shared__ int wred[16];

  const int w = blockIdx.x;          // lattice id
  const int t = threadIdx.x;
  const int c = w & 15;
  const int bp = slotmap[w];         // chain row, 0..15
  const float Tb = T[bp];
  const float p4 = (float)exp((double)(-4.0f / Tb));  // ref: f32 div, f32 exp
  const float p8 = (float)exp((double)(-8.0f / Tb));

  // load lattice: 1024 threads x 16 B (word t == segment this thread owns)
  ((uint4*)lat32)[t] = ((const uint4*)sg)[(w << 10) + t];
  __syncthreads();

  const int r    = t >> 3;           // row 0..127
  const int seg  = t & 7;            // 16-col segment 0..7
  const int col0 = seg << 4;
  const uint32_t rowbase = ((uint32_t)((bp << 4) | c) << 14) + ((uint32_t)r << 7);
  const int8_t* latb = (const int8_t*)lat32;

  for (int sw = 0; sw < nsw; ++sw) {
    uint4 kk;
    switch (sw) {
      case 0: kk = K0; break;
      case 1: kk = K1; break;
      case 2: kk = K2; break;
      case 3: kk = K3; break;
      default: kk = K4; break;
    }
    for (int par = 0; par < 2; ++par) {
      const uint32_t kk0 = par ? kk.z : kk.x;
      const uint32_t kk1 = par ? kk.w : kk.y;
      const int j0 = (r + par) & 1;  // parity offset of masked cols in this row

      uint4 cv = ((const uint4*)lat32)[(r << 3) + seg];
      uint4 uv = ((const uint4*)lat32)[(((r - 1) & 127) << 3) + seg];
      uint4 dv = ((const uint4*)lat32)[(((r + 1) & 127) << 3) + seg];
      int lfb = latb[(r << 7) + ((col0 - 1) & 127)];
      int rtb = latb[(r << 7) + ((col0 + 16) & 127)];

      uint32_t cw[4] = {cv.x, cv.y, cv.z, cv.w};
      uint32_t uw[4] = {uv.x, uv.y, uv.z, uv.w};
      uint32_t dw[4] = {dv.x, dv.y, dv.z, dv.w};

      // extended window X[0..17] = {lfb, cur[0..15], rtb}; Y byte k = X[k+j0]
      uint32_t ext[5];
      ext[0] = (cw[0] << 8) | (uint32_t)(uint8_t)lfb;
      ext[1] = (cw[0] >> 24) | (cw[1] << 8);
      ext[2] = (cw[1] >> 24) | (cw[2] << 8);
      ext[3] = (cw[2] >> 24) | (cw[3] << 8);
      ext[4] = (cw[3] >> 24) | ((uint32_t)(uint8_t)rtb << 8);
      uint32_t Y[5], U[4], D[4];
#pragma unroll
      for (int i = 0; i < 4; ++i) {
        uint32_t sh = (ext[i] >> 8) | (ext[i + 1] << 24);
        Y[i] = j0 ? sh : ext[i];
        uint32_t su = (uw[i] >> 8) | ((i < 3 ? uw[i + 1] : 0u) << 24);
        U[i] = j0 ? su : uw[i];
        uint32_t sd = (dw[i] >> 8) | ((i < 3 ? dw[i + 1] : 0u) << 24);
        D[i] = j0 ? sd : dw[i];
      }
      Y[4] = j0 ? (ext[4] >> 8) : ext[4];

      const uint32_t mbase = 0xFEu << (8 * j0);   // XOR flips 0x01<->0xFF
      uint32_t xm[4] = {0u, 0u, 0u, 0u};
      const uint32_t cnt0 = rowbase + (uint32_t)(col0 + j0);
#pragma unroll
      for (int m = 0; m < 8; ++m) {
        int lf = sb(Y[(2 * m) >> 2], (2 * m) & 3);
        int s0 = sb(Y[(2 * m + 1) >> 2], (2 * m + 1) & 3);
        int rt = sb(Y[(2 * m + 2) >> 2], (2 * m + 2) & 3);
        int up = sb(U[(2 * m) >> 2], (2 * m) & 3);
        int dn = sb(D[(2 * m) >> 2], (2 * m) & 3);
        int q = s0 * (lf + rt + up + dn);         // dE = 2*q
        uint32_t o0, o1;
        tf2x32(kk0, kk1, 0u, cnt0 + 2u * (uint32_t)m, o0, o1);
        float u = tf_uniform(o0 ^ o1);
        bool a = (q <= 0) || (u < (q == 4 ? p8 : p4));
        if (a) xm[m >> 1] |= (m & 1) ? (mbase << 16) : mbase;
      }
      uint4 nv;
      nv.x = cw[0] ^ xm[0]; nv.y = cw[1] ^ xm[1];
      nv.z = cw[2] ^ xm[2]; nv.w = cw[3] ^ xm[3];
      ((uint4*)lat32)[(r << 3) + seg] = nv;
      __syncthreads();
    }

    if (sw == sample_local) {
      // dump sample: out[bp][sidx*16+c][.][.] as float (own segment only)
      uint4 cv = ((const uint4*)lat32)[(r << 3) + seg];
      float4* dst = (float4*)out
                  + (((size_t)((bp << 5) + (sidx << 4) + c)) << 12)
                  + (r << 5) + (seg << 2);
      uint32_t wv[4] = {cv.x, cv.y, cv.z, cv.w};
#pragma unroll
      for (int q = 0; q < 4; ++q) {
        float4 f;
        f.x = (float)sb(wv[q], 0); f.y = (float)sb(wv[q], 1);
        f.z = (float)sb(wv[q], 2); f.w = (float)sb(wv[q], 3);
        dst[q] = f;
      }
    }
  }

  // store lattice back
  ((uint4*)sg)[(w << 10) + t] = ((const uint4*)lat32)[t];

  if (write_E) {
    // E = -sum s*(down+right), exact integer; chain-indexed slot
    uint4 cv = ((const uint4*)lat32)[(r << 3) + seg];
    uint4 dv = ((const uint4*)lat32)[(((r + 1) & 127) << 3) + seg];
    int rb = latb[(r << 7) + ((col0 + 16) & 127)];
    uint32_t cw[4] = {cv.x, cv.y, cv.z, cv.w};
    uint32_t dw[4] = {dv.x, dv.y, dv.z, dv.w};
    int psum = 0;
#pragma unroll
    for (int i = 0; i < 16; ++i) {
      int ci = sb(cw[i >> 2], i & 3);
      int di = sb(dw[i >> 2], i & 3);
      int ri = (i < 15) ? sb(cw[(i + 1) >> 2], (i + 1) & 3) : rb;
      psum += ci * (di + ri);
    }
#pragma unroll
    for (int o = 32; o > 0; o >>= 1) psum += __shfl_down(psum, o, 64);
    if ((t & 63) == 0) wred[t >> 6] = psum;
    __syncthreads();
    if (t == 0) {
      int tot = 0;
#pragma unroll
      for (int i = 0; i < 16; ++i) tot += wred[i];
      E[(bp << 4) | c] = -(float)tot;
    }
  }
}

// PT accept + slot relabel. 1 block of 128 threads, t = p*16+c.
__global__ __launch_bounds__(128) void k_decide(const float* __restrict__ E,
                                                const float* __restrict__ T,
                                                uint32_t pk0, uint32_t pk1,
                                                int* __restrict__ slotmap,
                                                int* __restrict__ occ) {
  int t = threadIdx.x;                         // < 128
  int p = t >> 4, c = t & 15;
  float E0 = E[(2 * p) * NC + c];
  float E1 = E[(2 * p + 1) * NC + c];
  float b0 = 1.0f / T[2 * p];
  float b1 = 1.0f / T[2 * p + 1];
  float d = (b0 - b1) * (E0 - E1);
  uint32_t w0, w1;
  tf2x32(pk0, pk1, 0u, (uint32_t)t, w0, w1);
  float u = tf_uniform(w0 ^ w1);
  float pa = (d < 0.0f) ? (float)exp((double)d) : 1.0f;
  if (u < pa) {
    int a = occ[(2 * p) * NC + c];       // lattice at row 2p, replica c
    int b = occ[(2 * p + 1) * NC + c];   // lattice at row 2p+1, replica c
    occ[(2 * p) * NC + c] = b;
    occ[(2 * p + 1) * NC + c] = a;
    slotmap[a] = 2 * p + 1;
    slotmap[b] = 2 * p;
  }
}

// ---------------- host ----------------
extern "C" void kernel_launch(void* const* d_in, const int* in_sizes, int n_in,
                              void* d_out, int out_size, void* d_ws, size_t ws_size,
                              hipStream_t stream) {
  const float* spins_in = (const float*)d_in[0];
  const float* T        = (const float*)d_in[1];
  uint32_t* s   = (uint32_t*)d_ws;                          // 4 MB lattice
  float*  E     = (float*)((char*)d_ws + (4u << 20));       // 1 KB
  int*  slotmap = (int*)((char*)d_ws + (4u << 20) + 1024);  // 1 KB
  int*  occ     = (int*)((char*)d_ws + (4u << 20) + 2048);  // 1 KB
  float*  out = (float*)d_out;

  k_init<<<NSITES / 4 / 256, 256, 0, stream>>>((const float4*)spins_in, s,
                                               slotmap, occ);

  const uint32_t bk0 = 0u, bk1 = 42u;   // jax.random.key(42)
  // chunks split at PT events (after sweeps 0,5,10,15); samples after 14,19
  const int starts[5]  = {0, 1, 6, 11, 16};
  const int counts[5]  = {1, 5, 5, 5, 4};
  const int samploc[5] = {-1, -1, -1, 3, 3};
  const int sampidx[5] = {0, 0, 0, 0, 1};
  const int writeE[5]  = {1, 1, 1, 1, 0};

  for (int ch = 0; ch < 5; ++ch) {
    uint4 K[5] = {{0,0,0,0},{0,0,0,0},{0,0,0,0},{0,0,0,0},{0,0,0,0}};
    for (int sw = 0; sw < counts[ch]; ++sw) {
      int i = starts[ch] + sw;
      uint32_t kk0, kk1, k1a, k1b, k2a, k2b;
      tf2x32(bk0, bk1, 0u, (uint32_t)i, kk0, kk1);   // fold_in(base, i)
      tf2x32(kk0, kk1, 0u, 0u, k1a, k1b);            // split -> k1 (black)
      tf2x32(kk0, kk1, 0u, 1u, k2a, k2b);            // split -> k2 (white)
      K[sw].x = k1a; K[sw].y = k1b; K[sw].z = k2a; K[sw].w = k2b;
    }
    k_chunk<<<256, 1024, 0, stream>>>(s, T, slotmap, E, out,
                                      K[0], K[1], K[2], K[3], K[4],
                                      counts[ch], samploc[ch], sampidx[ch],
                                      writeE[ch]);
    if (writeE[ch]) {
      int i = starts[ch] + counts[ch] - 1;           // 0,5,10,15
      uint32_t kk0, kk1, p0, p1;
      tf2x32(bk0, bk1, 0u, (uint32_t)i, kk0, kk1);
      tf2x32(kk0, kk1, 0u, 123u, p0, p1);            // fold_in(k, 123)
      k_decide<<<1, 128, 0, stream>>>(E, T, p0, p1, slotmap, occ);
    }
  }
}

// Round 7
// 290.574 us; speedup vs baseline: 2.0407x; 1.0050x over previous
//
#include <hip/hip_runtime.h>
#include <stdint.h>

// Ising PT sampler, bit-exact replay of JAX threefry2x32 (partitionable).
// R7: single fused chunk kernel, 5 launches total.
//  - 512 thr/block, 32 cols/thread: 2x work per barrier vs R6 (less jitter)
//  - init (chunk 0), PT decide (per-block own pair), keys, exp() all fused
//  - E ping-pong buffers across chunks; slotmap[w] = own chain row (0..15)
//  - no final lattice store-back

#define LSZ   128
#define NB    16
#define NC    16
#define NSITES (NB*NC*LSZ*LSZ)     // 4194304

// ---------------- threefry2x32 (JAX/Random123, 20 rounds) ----------------
__host__ __device__ __forceinline__ void tf2x32(uint32_t k0, uint32_t k1,
                                                uint32_t x0, uint32_t x1,
                                                uint32_t& o0, uint32_t& o1) {
  uint32_t k2 = k0 ^ k1 ^ 0x1BD11BDAu;
  x0 += k0; x1 += k1;
#define TFR(r) { x0 += x1; x1 = (x1 << (r)) | (x1 >> (32 - (r))); x1 ^= x0; }
  TFR(13) TFR(15) TFR(26) TFR(6)
  x0 += k1; x1 += k2 + 1u;
  TFR(17) TFR(29) TFR(16) TFR(24)
  x0 += k2; x1 += k0 + 2u;
  TFR(13) TFR(15) TFR(26) TFR(6)
  x0 += k0; x1 += k1 + 3u;
  TFR(17) TFR(29) TFR(16) TFR(24)
  x0 += k1; x1 += k2 + 4u;
  TFR(13) TFR(15) TFR(26) TFR(6)
  x0 += k2; x1 += k0 + 5u;
#undef TFR
  o0 = x0; o1 = x1;
}

__device__ __forceinline__ float tf_uniform(uint32_t w) {
  union { uint32_t u; float f; } cvt;
  cvt.u = (w >> 9) | 0x3f800000u;
  return cvt.f - 1.0f;
}

// signed byte b (compile-time 0..3) of word w
__device__ __forceinline__ int sb(uint32_t w, int b) {
  return (int)((int32_t)(w << ((3 - b) * 8)) >> 24);
}

// ---------------- the fused chunk kernel ----------------
// blockIdx.x = lattice id w (fixed storage slot). 512 threads:
// t>>2 = row (0..127), t&3 = 32-col segment.
__global__ __launch_bounds__(512) void k_chunk(const float4* __restrict__ in4,
                                               uint32_t* __restrict__ sg,
                                               const float* __restrict__ T,
                                               int* __restrict__ slotmap,
                                               const float* __restrict__ Eprev,
                                               float* __restrict__ Ecur,
                                               float* __restrict__ out,
                                               int chunk, int start, int nsw,
                                               int sample_local, int sidx,
                                               int write_E, int store_back) {
  __shared__ __align__(16) uint32_t lat32[LSZ * LSZ / 4];   // 16 KB
  __shared__ uint32_t kb[5][4];
  __shared__ float sh_p4, sh_p8;
  __shared__ int sh_bp;
  __shared__ int wred[8];

  const int w = blockIdx.x;
  const int t = threadIdx.x;
  const int c = w & 15;

  // per-sweep keys: fold_in(base, i) then foldlike split -> (black, white)
  if (t < nsw) {
    uint32_t kk0, kk1, a, b;
    tf2x32(0u, 42u, 0u, (uint32_t)(start + t), kk0, kk1);
    tf2x32(kk0, kk1, 0u, 0u, a, b);
    kb[t][0] = a; kb[t][1] = b;
    tf2x32(kk0, kk1, 0u, 1u, a, b);
    kb[t][2] = a; kb[t][3] = b;
  }

  // lattice load into LDS
  if (chunk == 0) {
    for (int k = 0; k < 8; ++k) {
      int idx = k * 512 + t;                 // word index 0..4095
      float4 v = in4[(w << 12) + idx];
      lat32[idx] = (v.x >= 0.0f ? 0x01u : 0xFFu)
                 | ((v.y >= 0.0f ? 0x01u : 0xFFu) << 8)
                 | ((v.z >= 0.0f ? 0x01u : 0xFFu) << 16)
                 | ((v.w >= 0.0f ? 0x01u : 0xFFu) << 24);
    }
  } else {
    for (int k = 0; k < 2; ++k)
      ((uint4*)lat32)[k * 512 + t] = ((const uint4*)sg)[(w << 10) + k * 512 + t];
  }

  // thread 0: apply previous PT event (chunks >=1), probs, publish
  if (t == 0) {
    int bp;
    if (chunk == 0) {
      bp = w >> 4;
    } else {
      bp = slotmap[w];
      int p = bp >> 1;
      float E0 = Eprev[(2 * p) * NC + c];
      float E1 = Eprev[(2 * p + 1) * NC + c];
      float b0 = 1.0f / T[2 * p];
      float b1 = 1.0f / T[2 * p + 1];
      float d = (b0 - b1) * (E0 - E1);
      uint32_t kk0, kk1, p0, p1, w0, w1;
      tf2x32(0u, 42u, 0u, (uint32_t)(start - 1), kk0, kk1);  // fold_in(base,i)
      tf2x32(kk0, kk1, 0u, 123u, p0, p1);                    // fold_in(k,123)
      tf2x32(p0, p1, 0u, (uint32_t)(p * NC + c), w0, w1);    // uniform elem
      float u = tf_uniform(w0 ^ w1);
      float pa = (d < 0.0f) ? (float)exp((double)d) : 1.0f;
      if (u < pa) bp ^= 1;
    }
    slotmap[w] = bp;
    sh_bp = bp;
    float Tb = T[bp];
    sh_p4 = (float)exp((double)(-4.0f / Tb));   // ref: f32 div, f32 exp
    sh_p8 = (float)exp((double)(-8.0f / Tb));
  }
  __syncthreads();

  const int bp = sh_bp;
  const float p4 = sh_p4, p8 = sh_p8;
  const int r    = t >> 2;          // row 0..127
  const int sg32 = t & 3;           // 32-col segment
  const int col0 = sg32 << 5;
  const uint32_t rowbase = ((uint32_t)((bp << 4) | c) << 14) + ((uint32_t)r << 7);
  const int8_t* latb = (const int8_t*)lat32;
  const int own4 = (r << 3) + (sg32 << 1);   // uint4 index of own segment

  for (int sw = 0; sw < nsw; ++sw) {
    for (int par = 0; par < 2; ++par) {
      const uint32_t kk0 = kb[sw][par * 2];
      const uint32_t kk1 = kb[sw][par * 2 + 1];
      const int j0 = (r + par) & 1;

      uint32_t cw[8], uw[8], dw[8];
      {
        uint4 a  = ((const uint4*)lat32)[own4];
        uint4 b2 = ((const uint4*)lat32)[own4 + 1];
        cw[0]=a.x; cw[1]=a.y; cw[2]=a.z; cw[3]=a.w;
        cw[4]=b2.x; cw[5]=b2.y; cw[6]=b2.z; cw[7]=b2.w;
        int u4 = (((r - 1) & 127) << 3) + (sg32 << 1);
        a  = ((const uint4*)lat32)[u4];
        b2 = ((const uint4*)lat32)[u4 + 1];
        uw[0]=a.x; uw[1]=a.y; uw[2]=a.z; uw[3]=a.w;
        uw[4]=b2.x; uw[5]=b2.y; uw[6]=b2.z; uw[7]=b2.w;
        int d4 = (((r + 1) & 127) << 3) + (sg32 << 1);
        a  = ((const uint4*)lat32)[d4];
        b2 = ((const uint4*)lat32)[d4 + 1];
        dw[0]=a.x; dw[1]=a.y; dw[2]=a.z; dw[3]=a.w;
        dw[4]=b2.x; dw[5]=b2.y; dw[6]=b2.z; dw[7]=b2.w;
      }
      int lfb = latb[(r << 7) + ((col0 - 1) & 127)];
      int rtb = latb[(r << 7) + ((col0 + 32) & 127)];

      // extended row window X[0..33] = {lfb, own[0..31], rtb}; Y = X >> j0
      uint32_t ex[9];
      ex[0] = (cw[0] << 8) | (uint32_t)(uint8_t)lfb;
#pragma unroll
      for (int i = 1; i < 8; ++i) ex[i] = (cw[i - 1] >> 24) | (cw[i] << 8);
      ex[8] = (cw[7] >> 24) | ((uint32_t)(uint8_t)rtb << 8);
      uint32_t Y[9], U[8], D[8];
#pragma unroll
      for (int i = 0; i < 8; ++i) {
        Y[i] = j0 ? ((ex[i] >> 8) | (ex[i + 1] << 24)) : ex[i];
        U[i] = j0 ? ((uw[i] >> 8) | ((i < 7 ? uw[i + 1] : 0u) << 24)) : uw[i];
        D[i] = j0 ? ((dw[i] >> 8) | ((i < 7 ? dw[i + 1] : 0u) << 24)) : dw[i];
      }
      Y[8] = j0 ? (ex[8] >> 8) : ex[8];

      const uint32_t mbase = 0xFEu << (8 * j0);   // XOR flips 0x01<->0xFF
      uint32_t xm[8];
#pragma unroll
      for (int i = 0; i < 8; ++i) xm[i] = 0u;
      const uint32_t cnt0 = rowbase + (uint32_t)(col0 + j0);
#pragma unroll
      for (int m = 0; m < 16; ++m) {
        int lf = sb(Y[(2 * m) >> 2], (2 * m) & 3);
        int s0 = sb(Y[(2 * m + 1) >> 2], (2 * m + 1) & 3);
        int rt = sb(Y[(2 * m + 2) >> 2], (2 * m + 2) & 3);
        int up = sb(U[(2 * m) >> 2], (2 * m) & 3);
        int dn = sb(D[(2 * m) >> 2], (2 * m) & 3);
        int q = s0 * (lf + rt + up + dn);         // dE = 2*q
        uint32_t o0, o1;
        tf2x32(kk0, kk1, 0u, cnt0 + 2u * (uint32_t)m, o0, o1);
        float u = tf_uniform(o0 ^ o1);
        bool a = (q <= 0) || (u < (q == 4 ? p8 : p4));
        if (a) xm[m >> 1] |= (m & 1) ? (mbase << 16) : mbase;
      }
      uint4 n0, n1;
      n0.x = cw[0] ^ xm[0]; n0.y = cw[1] ^ xm[1];
      n0.z = cw[2] ^ xm[2]; n0.w = cw[3] ^ xm[3];
      n1.x = cw[4] ^ xm[4]; n1.y = cw[5] ^ xm[5];
      n1.z = cw[6] ^ xm[6]; n1.w = cw[7] ^ xm[7];
      ((uint4*)lat32)[own4]     = n0;
      ((uint4*)lat32)[own4 + 1] = n1;
      __syncthreads();
    }

    if (sw == sample_local) {
      // out[bp][sidx*16+c][r][col0..col0+31] as float
      float4* dst = (float4*)out
                  + (((size_t)((bp << 5) + (sidx << 4) + c)) << 12)
                  + (r << 5) + (sg32 << 3);
      const uint32_t* own = lat32 + (r << 5) + (sg32 << 3);
#pragma unroll
      for (int qd = 0; qd < 8; ++qd) {
        uint32_t v = own[qd];
        float4 f;
        f.x = (float)sb(v, 0); f.y = (float)sb(v, 1);
        f.z = (float)sb(v, 2); f.w = (float)sb(v, 3);
        dst[qd] = f;
      }
    }
  }

  if (write_E) {
    // E = -sum s*(down+right), exact integer in f32
    uint32_t cw[8], dw[8];
    {
      uint4 a  = ((const uint4*)lat32)[own4];
      uint4 b2 = ((const uint4*)lat32)[own4 + 1];
      cw[0]=a.x; cw[1]=a.y; cw[2]=a.z; cw[3]=a.w;
      cw[4]=b2.x; cw[5]=b2.y; cw[6]=b2.z; cw[7]=b2.w;
      int d4 = (((r + 1) & 127) << 3) + (sg32 << 1);
      a  = ((const uint4*)lat32)[d4];
      b2 = ((const uint4*)lat32)[d4 + 1];
      dw[0]=a.x; dw[1]=a.y; dw[2]=a.z; dw[3]=a.w;
      dw[4]=b2.x; dw[5]=b2.y; dw[6]=b2.z; dw[7]=b2.w;
    }
    int rb = latb[(r << 7) + ((col0 + 32) & 127)];
    int psum = 0;
#pragma unroll
    for (int i = 0; i < 32; ++i) {
      int ci = sb(cw[i >> 2], i & 3);
      int di = sb(dw[i >> 2], i & 3);
      int ri = (i < 31) ? sb(cw[(i + 1) >> 2], (i + 1) & 3) : rb;
      psum += ci * (di + ri);
    }
#pragma unroll
    for (int o = 32; o > 0; o >>= 1) psum += __shfl_down(psum, o, 64);
    if ((t & 63) == 0) wred[t >> 6] = psum;
    __syncthreads();
    if (t == 0) {
      int tot = 0;
#pragma unroll
      for (int i = 0; i < 8; ++i) tot += wred[i];
      Ecur[(bp << 4) | c] = -(float)tot;
    }
  }

  if (store_back) {
    for (int k = 0; k < 2; ++k)
      ((uint4*)sg)[(w << 10) + k * 512 + t] = ((const uint4*)lat32)[k * 512 + t];
  }
}

// ---------------- host ----------------
extern "C" void kernel_launch(void* const* d_in, const int* in_sizes, int n_in,
                              void* d_out, int out_size, void* d_ws, size_t ws_size,
                              hipStream_t stream) {
  const float* spins_in = (const float*)d_in[0];
  const float* T        = (const float*)d_in[1];
  uint32_t* s   = (uint32_t*)d_ws;                          // 4 MB lattice
  float*  Ea    = (float*)((char*)d_ws + (4u << 20));       // 1 KB
  float*  Eb    = (float*)((char*)d_ws + (4u << 20) + 1024);
  int*  slotmap = (int*)((char*)d_ws + (4u << 20) + 2048);  // 1 KB
  float*  out = (float*)d_out;

  // chunks split at PT events (after sweeps 0,5,10,15); samples after 14,19
  const int starts[5]  = {0, 1, 6, 11, 16};
  const int counts[5]  = {1, 5, 5, 5, 4};
  const int samploc[5] = {-1, -1, -1, 3, 3};
  const int sampidx[5] = {0, 0, 0, 0, 1};
  const int writeE[5]  = {1, 1, 1, 1, 0};
  const int storeB[5]  = {1, 1, 1, 1, 0};

  for (int ch = 0; ch < 5; ++ch) {
    float* Ecur  = (ch & 1) ? Eb : Ea;
    float* Eprev = (ch & 1) ? Ea : Eb;   // chunk ch-1 wrote bufs[(ch-1)&1]
    k_chunk<<<256, 512, 0, stream>>>((const float4*)spins_in, s, T, slotmap,
                                     Eprev, Ecur, out,
                                     ch, starts[ch], counts[ch],
                                     samploc[ch], sampidx[ch],
                                     writeE[ch], storeB[ch]);
  }
}

// Round 8
// 283.458 us; speedup vs baseline: 2.0920x; 1.0251x over previous
//
#include <hip/hip_runtime.h>
#include <stdint.h>

// Ising PT sampler, bit-exact replay of JAX threefry2x32 (partitionable).
// R8: R6 geometry (1024 thr/block, 16 cols/thread) + R7 fusion (5 launches) +
//  - dual-interleaved threefry (2 independent chains -> hides dep latency)
//  - rotates via __builtin_rotateleft32 (v_alignbit)
//  - integer-threshold accept test: u < p  <=>  (bits>>9) < ceil(p*2^23)
//    (exact equivalence; bitstream unchanged)

#define LSZ   128
#define NB    16
#define NC    16
#define NSITES (NB*NC*LSZ*LSZ)     // 4194304

// ---------------- threefry2x32 (JAX/Random123, 20 rounds) ----------------
__host__ __device__ __forceinline__ void tf2x32(uint32_t k0, uint32_t k1,
                                                uint32_t x0, uint32_t x1,
                                                uint32_t& o0, uint32_t& o1) {
  uint32_t k2 = k0 ^ k1 ^ 0x1BD11BDAu;
  x0 += k0; x1 += k1;
#define TFR(r) { x0 += x1; x1 = (x1 << (r)) | (x1 >> (32 - (r))); x1 ^= x0; }
  TFR(13) TFR(15) TFR(26) TFR(6)
  x0 += k1; x1 += k2 + 1u;
  TFR(17) TFR(29) TFR(16) TFR(24)
  x0 += k2; x1 += k0 + 2u;
  TFR(13) TFR(15) TFR(26) TFR(6)
  x0 += k0; x1 += k1 + 3u;
  TFR(17) TFR(29) TFR(16) TFR(24)
  x0 += k1; x1 += k2 + 4u;
  TFR(13) TFR(15) TFR(26) TFR(6)
  x0 += k2; x1 += k0 + 5u;
#undef TFR
  o0 = x0; o1 = x1;
}

// dual-block threefry: counters (0,xa) and (0,xb), same key. Two independent
// dependency chains interleaved for ILP. Bit-identical to tf2x32 per block.
__device__ __forceinline__ void tf2x32x2(uint32_t k0, uint32_t k1,
                                         uint32_t xa, uint32_t xb,
                                         uint32_t& oa, uint32_t& ob) {
  uint32_t k2 = k0 ^ k1 ^ 0x1BD11BDAu;
  uint32_t a0 = k0, a1 = xa + k1;
  uint32_t b0 = k0, b1 = xb + k1;
#define TFR2(r) { a0 += a1; b0 += b1; \
                  a1 = __builtin_rotateleft32(a1, r); \
                  b1 = __builtin_rotateleft32(b1, r); \
                  a1 ^= a0; b1 ^= b0; }
  TFR2(13) TFR2(15) TFR2(26) TFR2(6)
  a0 += k1; a1 += k2 + 1u; b0 += k1; b1 += k2 + 1u;
  TFR2(17) TFR2(29) TFR2(16) TFR2(24)
  a0 += k2; a1 += k0 + 2u; b0 += k2; b1 += k0 + 2u;
  TFR2(13) TFR2(15) TFR2(26) TFR2(6)
  a0 += k0; a1 += k1 + 3u; b0 += k0; b1 += k1 + 3u;
  TFR2(17) TFR2(29) TFR2(16) TFR2(24)
  a0 += k1; a1 += k2 + 4u; b0 += k1; b1 += k2 + 4u;
  TFR2(13) TFR2(15) TFR2(26) TFR2(6)
  a0 += k2; a1 += k0 + 5u; b0 += k2; b1 += k0 + 5u;
#undef TFR2
  oa = a0 ^ a1;                 // random_bits = o0 ^ o1 (partitionable)
  ob = b0 ^ b1;
}

__device__ __forceinline__ float tf_uniform(uint32_t w) {
  union { uint32_t u; float f; } cvt;
  cvt.u = (w >> 9) | 0x3f800000u;
  return cvt.f - 1.0f;
}

// signed byte b (compile-time 0..3) of word w
__device__ __forceinline__ int sb(uint32_t w, int b) {
  return (int)((int32_t)(w << ((3 - b) * 8)) >> 24);
}

// ---------------- the fused chunk kernel ----------------
// blockIdx.x = lattice id w. 1024 threads: t>>3 = row, t&7 = 16-col segment.
__global__ __launch_bounds__(1024) void k_chunk(const float4* __restrict__ in4,
                                                uint32_t* __restrict__ sg,
                                                const float* __restrict__ T,
                                                int* __restrict__ slotmap,
                                                const float* __restrict__ Eprev,
                                                float* __restrict__ Ecur,
                                                float* __restrict__ out,
                                                int chunk, int start, int nsw,
                                                int sample_local, int sidx,
                                                int write_E, int store_back) {
  __shared__ __align__(16) uint32_t lat32[LSZ * LSZ / 4];   // 16 KB
  __shared__ uint32_t kb[5][4];
  __shared__ uint32_t sh_T4, sh_T8;
  __shared__ int sh_bp;
  __shared__ int wred[16];

  const int w = blockIdx.x;
  const int t = threadIdx.x;
  const int c = w & 15;

  // per-sweep keys: fold_in(base, i) then foldlike split -> (black, white)
  if (t < nsw) {
    uint32_t kk0, kk1, a, b;
    tf2x32(0u, 42u, 0u, (uint32_t)(start + t), kk0, kk1);
    tf2x32(kk0, kk1, 0u, 0u, a, b);
    kb[t][0] = a; kb[t][1] = b;
    tf2x32(kk0, kk1, 0u, 1u, a, b);
    kb[t][2] = a; kb[t][3] = b;
  }

  // lattice load into LDS
  if (chunk == 0) {
    for (int k = 0; k < 4; ++k) {
      int idx = k * 1024 + t;                // word index 0..4095
      float4 v = in4[(w << 12) + idx];
      lat32[idx] = (v.x >= 0.0f ? 0x01u : 0xFFu)
                 | ((v.y >= 0.0f ? 0x01u : 0xFFu) << 8)
                 | ((v.z >= 0.0f ? 0x01u : 0xFFu) << 16)
                 | ((v.w >= 0.0f ? 0x01u : 0xFFu) << 24);
    }
  } else {
    ((uint4*)lat32)[t] = ((const uint4*)sg)[(w << 10) + t];
  }

  // thread 0: apply previous PT event (chunks >=1), probs, publish
  if (t == 0) {
    int bp;
    if (chunk == 0) {
      bp = w >> 4;
    } else {
      bp = slotmap[w];
      int p = bp >> 1;
      float E0 = Eprev[(2 * p) * NC + c];
      float E1 = Eprev[(2 * p + 1) * NC + c];
      float b0 = 1.0f / T[2 * p];
      float b1 = 1.0f / T[2 * p + 1];
      float d = (b0 - b1) * (E0 - E1);
      uint32_t kk0, kk1, p0, p1, w0, w1;
      tf2x32(0u, 42u, 0u, (uint32_t)(start - 1), kk0, kk1);  // fold_in(base,i)
      tf2x32(kk0, kk1, 0u, 123u, p0, p1);                    // fold_in(k,123)
      tf2x32(p0, p1, 0u, (uint32_t)(p * NC + c), w0, w1);    // uniform elem
      float u = tf_uniform(w0 ^ w1);
      float pa = (d < 0.0f) ? (float)exp((double)d) : 1.0f;
      if (u < pa) bp ^= 1;
    }
    slotmap[w] = bp;
    sh_bp = bp;
    float Tb = T[bp];
    float p4 = (float)exp((double)(-4.0f / Tb));   // ref: f32 div, f32 exp
    float p8 = (float)exp((double)(-8.0f / Tb));
    // u < p  <=>  (bits>>9) < ceil(p * 2^23), exactly (u-values are v*2^-23)
    sh_T4 = (uint32_t)ceil((double)p4 * 8388608.0);
    sh_T8 = (uint32_t)ceil((double)p8 * 8388608.0);
  }
  __syncthreads();

  const int bp = sh_bp;
  const uint32_t T4 = sh_T4, T8 = sh_T8;
  const uint32_t TOPEN = 0x00800000u;   // accept-all (bits>>9 <= 0x7FFFFF)
  const int r    = t >> 3;          // row 0..127
  const int seg  = t & 7;           // 16-col segment
  const int col0 = seg << 4;
  const uint32_t rowbase = ((uint32_t)((bp << 4) | c) << 14) + ((uint32_t)r << 7);
  const int8_t* latb = (const int8_t*)lat32;
  const int own4 = (r << 3) + seg;

  for (int sw = 0; sw < nsw; ++sw) {
    for (int par = 0; par < 2; ++par) {
      const uint32_t kk0 = kb[sw][par * 2];
      const uint32_t kk1 = kb[sw][par * 2 + 1];
      const int j0 = (r + par) & 1;

      uint4 cv = ((const uint4*)lat32)[own4];
      uint4 uv = ((const uint4*)lat32)[(((r - 1) & 127) << 3) + seg];
      uint4 dv = ((const uint4*)lat32)[(((r + 1) & 127) << 3) + seg];
      int lfb = latb[(r << 7) + ((col0 - 1) & 127)];
      int rtb = latb[(r << 7) + ((col0 + 16) & 127)];

      uint32_t cw[4] = {cv.x, cv.y, cv.z, cv.w};
      uint32_t uw[4] = {uv.x, uv.y, uv.z, uv.w};
      uint32_t dw[4] = {dv.x, dv.y, dv.z, dv.w};

      // extended window X[0..17] = {lfb, own[0..15], rtb}; Y byte k = X[k+j0]
      uint32_t ext[5];
      ext[0] = (cw[0] << 8) | (uint32_t)(uint8_t)lfb;
      ext[1] = (cw[0] >> 24) | (cw[1] << 8);
      ext[2] = (cw[1] >> 24) | (cw[2] << 8);
      ext[3] = (cw[2] >> 24) | (cw[3] << 8);
      ext[4] = (cw[3] >> 24) | ((uint32_t)(uint8_t)rtb << 8);
      uint32_t Y[5], U[4], D[4];
#pragma unroll
      for (int i = 0; i < 4; ++i) {
        uint32_t sh = (ext[i] >> 8) | (ext[i + 1] << 24);
        Y[i] = j0 ? sh : ext[i];
        uint32_t su = (uw[i] >> 8) | ((i < 3 ? uw[i + 1] : 0u) << 24);
        U[i] = j0 ? su : uw[i];
        uint32_t sd = (dw[i] >> 8) | ((i < 3 ? dw[i + 1] : 0u) << 24);
        D[i] = j0 ? sd : dw[i];
      }
      Y[4] = j0 ? (ext[4] >> 8) : ext[4];

      const uint32_t mbase = 0xFEu << (8 * j0);   // XOR flips 0x01<->0xFF
      uint32_t xm[4] = {0u, 0u, 0u, 0u};
      const uint32_t cnt0 = rowbase + (uint32_t)(col0 + j0);
#pragma unroll
      for (int m2 = 0; m2 < 4; ++m2) {
        const int ma = 2 * m2, mb = 2 * m2 + 1;
        int lfa = sb(Y[(2 * ma) >> 2], (2 * ma) & 3);
        int s0a = sb(Y[(2 * ma + 1) >> 2], (2 * ma + 1) & 3);
        int rta = sb(Y[(2 * ma + 2) >> 2], (2 * ma + 2) & 3);
        int upa = sb(U[(2 * ma) >> 2], (2 * ma) & 3);
        int dna = sb(D[(2 * ma) >> 2], (2 * ma) & 3);
        int qa = s0a * (lfa + rta + upa + dna);
        int lfb2 = sb(Y[(2 * mb) >> 2], (2 * mb) & 3);
        int s0b = sb(Y[(2 * mb + 1) >> 2], (2 * mb + 1) & 3);
        int rtb2 = sb(Y[(2 * mb + 2) >> 2], (2 * mb + 2) & 3);
        int upb = sb(U[(2 * mb) >> 2], (2 * mb) & 3);
        int dnb = sb(D[(2 * mb) >> 2], (2 * mb) & 3);
        int qb = s0b * (lfb2 + rtb2 + upb + dnb);
        uint32_t wa, wb;
        tf2x32x2(kk0, kk1, cnt0 + 2u * (uint32_t)ma, cnt0 + 2u * (uint32_t)mb,
                 wa, wb);
        uint32_t ta = (qa <= 0) ? TOPEN : (qa == 4 ? T8 : T4);
        uint32_t tb = (qb <= 0) ? TOPEN : (qb == 4 ? T8 : T4);
        if ((wa >> 9) < ta) xm[m2] |= mbase;
        if ((wb >> 9) < tb) xm[m2] |= (mbase << 16);
      }
      uint4 nv;
      nv.x = cw[0] ^ xm[0]; nv.y = cw[1] ^ xm[1];
      nv.z = cw[2] ^ xm[2]; nv.w = cw[3] ^ xm[3];
      ((uint4*)lat32)[own4] = nv;
      __syncthreads();
    }

    if (sw == sample_local) {
      // out[bp][sidx*16+c][r][col0..col0+15] as float
      uint4 cv = ((const uint4*)lat32)[own4];
      float4* dst = (float4*)out
                  + (((size_t)((bp << 5) + (sidx << 4) + c)) << 12)
                  + (r << 5) + (seg << 2);
      uint32_t wv[4] = {cv.x, cv.y, cv.z, cv.w};
#pragma unroll
      for (int qd = 0; qd < 4; ++qd) {
        float4 f;
        f.x = (float)sb(wv[qd], 0); f.y = (float)sb(wv[qd], 1);
        f.z = (float)sb(wv[qd], 2); f.w = (float)sb(wv[qd], 3);
        dst[qd] = f;
      }
    }
  }

  if (write_E) {
    // E = -sum s*(down+right), exact integer in f32
    uint4 cv = ((const uint4*)lat32)[own4];
    uint4 dv = ((const uint4*)lat32)[(((r + 1) & 127) << 3) + seg];
    int rb = latb[(r << 7) + ((col0 + 16) & 127)];
    uint32_t cw[4] = {cv.x, cv.y, cv.z, cv.w};
    uint32_t dw[4] = {dv.x, dv.y, dv.z, dv.w};
    int psum = 0;
#pragma unroll
    for (int i = 0; i < 16; ++i) {
      int ci = sb(cw[i >> 2], i & 3);
      int di = sb(dw[i >> 2], i & 3);
      int ri = (i < 15) ? sb(cw[(i + 1) >> 2], (i + 1) & 3) : rb;
      psum += ci * (di + ri);
    }
#pragma unroll
    for (int o = 32; o > 0; o >>= 1) psum += __shfl_down(psum, o, 64);
    if ((t & 63) == 0) wred[t >> 6] = psum;
    __syncthreads();
    if (t == 0) {
      int tot = 0;
#pragma unroll
      for (int i = 0; i < 16; ++i) tot += wred[i];
      Ecur[(bp << 4) | c] = -(float)tot;
    }
  }

  if (store_back) {
    ((uint4*)sg)[(w << 10) + t] = ((const uint4*)lat32)[t];
  }
}

// ---------------- host ----------------
extern "C" void kernel_launch(void* const* d_in, const int* in_sizes, int n_in,
                              void* d_out, int out_size, void* d_ws, size_t ws_size,
                              hipStream_t stream) {
  const float* spins_in = (const float*)d_in[0];
  const float* T        = (const float*)d_in[1];
  uint32_t* s   = (uint32_t*)d_ws;                          // 4 MB lattice
  float*  Ea    = (float*)((char*)d_ws + (4u << 20));       // 1 KB
  float*  Eb    = (float*)((char*)d_ws + (4u << 20) + 1024);
  int*  slotmap = (int*)((char*)d_ws + (4u << 20) + 2048);  // 1 KB
  float*  out = (float*)d_out;

  // chunks split at PT events (after sweeps 0,5,10,15); samples after 14,19
  const int starts[5]  = {0, 1, 6, 11, 16};
  const int counts[5]  = {1, 5, 5, 5, 4};
  const int samploc[5] = {-1, -1, -1, 3, 3};
  const int sampidx[5] = {0, 0, 0, 0, 1};
  const int writeE[5]  = {1, 1, 1, 1, 0};
  const int storeB[5]  = {1, 1, 1, 1, 0};

  for (int ch = 0; ch < 5; ++ch) {
    float* Ecur  = (ch & 1) ? Eb : Ea;
    float* Eprev = (ch & 1) ? Ea : Eb;
    k_chunk<<<256, 1024, 0, stream>>>((const float4*)spins_in, s, T, slotmap,
                                      Eprev, Ecur, out,
                                      ch, starts[ch], counts[ch],
                                      samploc[ch], sampidx[ch],
                                      writeE[ch], storeB[ch]);
  }
}